// Round 8
// baseline (9229.066 us; speedup 1.0000x reference)
//
#include <hip/hip_runtime.h>
#include <hip/hip_bf16.h>

#define SEQ    4096
// xg layout: [t][blkc(2)][ctid(512)][48B]: per consumer thread r/z/n uint4 at
// +0/+16/+32; within gate: jt0 8B, jt1 8B (4 bf16 j-values each).
#define SLAB   49152

typedef __attribute__((ext_vector_type(8))) short bf16x8;
typedef __attribute__((ext_vector_type(4))) float f32x4;

__device__ __forceinline__ unsigned int pkbf(float a, float b) {
    __hip_bfloat162 h = __float22bfloat162_rn(make_float2(a, b));
    union { __hip_bfloat162 h2; unsigned int u; } c; c.h2 = h; return c.u;
}
__device__ __forceinline__ float bflo(unsigned int q) { return __uint_as_float(q << 16); }
__device__ __forceinline__ float bfhi(unsigned int q) { return __uint_as_float(q & 0xFFFF0000u); }

// ---------------------------------------------------------------------------
// Kernel B: x_proj = x @ W_ih^T (scaled, bias-folded), bf16, operand-swapped:
// A = W_ih (gate rows), B = x^T (batch cols) -> C[gate j][batch].
// Stores directly into the scan's consumer-thread-contiguous layout.
// grid (SEQ/32, 2), block 512. (unchanged — verified)
// ---------------------------------------------------------------------------
__global__ __launch_bounds__(512, 2) void gru_xproj(
    const float* __restrict__ x, const float* __restrict__ w_ih,
    const float* __restrict__ b_ih, const float* __restrict__ b_hh,
    char* __restrict__ xg)
{
    __shared__ __align__(16) char xlds[2][16384];
    const int tid = threadIdx.x;
    const int lane = tid & 63, wave = tid >> 6;
    const int l15 = lane & 15, l4 = lane >> 4;
    const int t0 = blockIdx.x * 32;
    const int gw0 = blockIdx.y * 384 + wave * 48;

    bf16x8 wa[3][8];
    float bias[3][4];
    int coff[3];
    #pragma unroll
    for (int gt = 0; gt < 3; ++gt) {
        const int T = gw0 + gt * 16;
        const float s = (T < 256) ? -1.442695041f : ((T < 512) ? 1.442695041f : 2.885390082f);
        const int row = T + l15;
        #pragma unroll
        for (int kk = 0; kk < 8; ++kk) {
            const float* p = w_ih + row * 256 + kk * 32 + l4 * 8;
            float4 aa = *(const float4*)p;
            float4 bb = *(const float4*)(p + 4);
            union { bf16x8 v; unsigned int u[4]; } f;
            f.u[0] = pkbf(s * aa.x, s * aa.y); f.u[1] = pkbf(s * aa.z, s * aa.w);
            f.u[2] = pkbf(s * bb.x, s * bb.y); f.u[3] = pkbf(s * bb.z, s * bb.w);
            wa[gt][kk] = f.v;
        }
        #pragma unroll
        for (int q = 0; q < 4; ++q) {
            const int g = T + 4 * l4 + q;
            bias[gt][q] = (g < 512) ? s * (b_ih[g] + b_hh[g]) : s * b_ih[g];
        }
        const int gi = T >> 8;
        const int jg = (T & 255) + 4 * l4;
        const int cw = jg >> 5;
        const int jt = (jg >> 4) & 1;
        const int ctid = cw * 64 + (l4 & 3) * 16 + l15;
        coff[gt] = ctid * 48 + gi * 16 + jt * 8;
    }

    for (int tt = 0; tt < 32; ++tt) {
        const int t = t0 + tt;
        const int buf = tt & 1;
        {
            const int b  = tid >> 4;
            const int k0 = (tid & 15) * 16;
            const float* xp = x + ((size_t)b * SEQ + t) * 256 + k0;
            float4 u0 = *(const float4*)(xp + 0);
            float4 u1 = *(const float4*)(xp + 4);
            float4 u2 = *(const float4*)(xp + 8);
            float4 u3 = *(const float4*)(xp + 12);
            union { bf16x8 v; unsigned int u[4]; } w0, w1;
            w0.u[0] = pkbf(u0.x,u0.y); w0.u[1] = pkbf(u0.z,u0.w);
            w0.u[2] = pkbf(u1.x,u1.y); w0.u[3] = pkbf(u1.z,u1.w);
            w1.u[0] = pkbf(u2.x,u2.y); w1.u[1] = pkbf(u2.z,u2.w);
            w1.u[2] = pkbf(u3.x,u3.y); w1.u[3] = pkbf(u3.z,u3.w);
            const int a0 = (b >> 4) * 8192 + (k0 >> 5) * 1024 + ((k0 >> 3) & 3) * 256 + (b & 15) * 16;
            *(bf16x8*)(xlds[buf] + a0      ) = w0.v;
            *(bf16x8*)(xlds[buf] + a0 + 256) = w1.v;
        }
        __syncthreads();

        f32x4 acc[3][2];
        #pragma unroll
        for (int gt = 0; gt < 3; ++gt)
            #pragma unroll
            for (int bt = 0; bt < 2; ++bt)
                acc[gt][bt] = (f32x4){bias[gt][0], bias[gt][1], bias[gt][2], bias[gt][3]};

        #pragma unroll
        for (int kk = 0; kk < 8; ++kk) {
            bf16x8 b0 = *(const bf16x8*)(xlds[buf] + (       kk * 1024 + l4 * 256 + l15 * 16));
            bf16x8 b1 = *(const bf16x8*)(xlds[buf] + (8192 + kk * 1024 + l4 * 256 + l15 * 16));
            #pragma unroll
            for (int gt = 0; gt < 3; ++gt) {
                acc[gt][0] = __builtin_amdgcn_mfma_f32_16x16x32_bf16(wa[gt][kk], b0, acc[gt][0], 0, 0, 0);
                acc[gt][1] = __builtin_amdgcn_mfma_f32_16x16x32_bf16(wa[gt][kk], b1, acc[gt][1], 0, 0, 0);
            }
        }
        #pragma unroll
        for (int bt = 0; bt < 2; ++bt)
            #pragma unroll
            for (int gt = 0; gt < 3; ++gt) {
                uint2 q;
                q.x = pkbf(acc[gt][bt][0], acc[gt][bt][1]);
                q.y = pkbf(acc[gt][bt][2], acc[gt][bt][3]);
                *(uint2*)(xg + (size_t)t * SLAB + bt * 24576 + coff[gt]) = q;
            }
    }
}

// ---------------------------------------------------------------------------
// Kernel C: persistent GRU scan, operand-swapped. grid(2): block b: batches
// [16b,16b+16). 8 waves; wave w owns hidden cols [32w,32w+32) x 3 gates.
// ALL 6 weight tiles in the unified VGPR/AGPR file (192 regs) -- zero weight
// re-reads. h double-buffered bf16 in LDS (16KB static), K-sliced layout,
// imm-offset conflict-free reads. Distance-1 xq prefetch (1 slot, 12 regs).
// Raw s_barrier + lgkmcnt(0) only; xq prefetch & out stores stay in flight.
// ---------------------------------------------------------------------------
__global__ __launch_bounds__(512, 2) void gru_rec(
    const float* __restrict__ w_hh, const float* __restrict__ b_hh,
    const float* __restrict__ h0, const char* __restrict__ xg,
    float* __restrict__ out)
{
    __shared__ __align__(16) char hb[2][8192];  // [buf][kk(8)][slot(4)][b(16)][16B]
    const int tid = threadIdx.x, lane = tid & 63, wave = tid >> 6;
    const int l15 = lane & 15, l4 = lane >> 4;
    const int blk = blockIdx.x;
    const int j0 = wave * 32;

    // all 6 A-tiles (r,z,n x jt0,jt1), scaled, resident: 192 regs
    bf16x8 wf[6][8];
    #pragma unroll
    for (int g6 = 0; g6 < 6; ++g6) {
        const int gate = g6 >> 1, jt = g6 & 1;
        const int row = gate * 256 + j0 + jt * 16 + l15;
        const float s = (gate == 0) ? -1.442695041f : ((gate == 1) ? 1.442695041f : 2.885390082f);
        #pragma unroll
        for (int kk = 0; kk < 8; ++kk) {
            const float* p = w_hh + row * 256 + kk * 32 + l4 * 8;
            float4 aa = *(const float4*)p;
            float4 bb = *(const float4*)(p + 4);
            union { bf16x8 v; unsigned int u[4]; } f;
            f.u[0] = pkbf(s * aa.x, s * aa.y); f.u[1] = pkbf(s * aa.z, s * aa.w);
            f.u[2] = pkbf(s * bb.x, s * bb.y); f.u[3] = pkbf(s * bb.z, s * bb.w);
            wf[g6][kk] = f.v;
        }
    }
    // n-gate b_hh, scaled, packed bf16
    uint2 bHnP[2];
    #pragma unroll
    for (int jt = 0; jt < 2; ++jt) {
        const int j = j0 + jt * 16 + 4 * l4;
        bHnP[jt].x = pkbf(2.885390082f * b_hh[512 + j + 0], 2.885390082f * b_hh[512 + j + 1]);
        bHnP[jt].y = pkbf(2.885390082f * b_hh[512 + j + 2], 2.885390082f * b_hh[512 + j + 3]);
    }

    // LDS bases (all per-step offsets are compile-time immediates)
    char* hwp = &hb[0][0] + (wave * 1024 + (l4 >> 1) * 256 + (l4 & 1) * 8 + l15 * 16);
    const char* hrp = &hb[0][0] + (l4 * 256 + l15 * 16);

    // initial h
    float hprev[2][4];
    #pragma unroll
    for (int jt = 0; jt < 2; ++jt) {
        const float* hp0 = h0 + (blk * 16 + l15) * 256 + j0 + jt * 16 + 4 * l4;
        float4 h4 = *(const float4*)hp0;
        hprev[jt][0] = h4.x; hprev[jt][1] = h4.y; hprev[jt][2] = h4.z; hprev[jt][3] = h4.w;
        uint2 hq;
        hq.x = pkbf(h4.x, h4.y); hq.y = pkbf(h4.z, h4.w);
        *(uint2*)(hwp + jt * 512) = hq;
    }

    const char* xqb = xg + blk * 24576 + tid * 48;
    char* op = (char*)out + ((size_t)(blk * 16 + l15) * SEQ * 256 + j0 + 4 * l4) * 4;

    // distance-1 prefetch: single slot (12 regs)
    uint4 xq0 = *(const uint4*)(xqb + 0);
    uint4 xq1 = *(const uint4*)(xqb + 16);
    uint4 xq2 = *(const uint4*)(xqb + 32);
    const char* xqn = xqb + SLAB;

    asm volatile("s_waitcnt lgkmcnt(0)" ::: "memory");
    __builtin_amdgcn_s_barrier();
    __builtin_amdgcn_sched_barrier(0);

#define GATES(P_, JT_, AR, AZ, AN, QX, QY) do { \
    float xn[4] = { bflo(QX), bfhi(QX), bflo(QY), bfhi(QY) }; \
    _Pragma("unroll") for (int i = 0; i < 4; ++i) { \
        float r   = __builtin_amdgcn_rcpf(1.0f + __builtin_amdgcn_exp2f(AR[i])); \
        float uu  = __builtin_amdgcn_rcpf(1.0f + __builtin_amdgcn_exp2f(AZ[i])); \
        float pre = fmaf(r, AN[i], xn[i]); \
        float nn  = fmaf(-2.0f, __builtin_amdgcn_rcpf(1.0f + __builtin_amdgcn_exp2f(pre)), 1.0f); \
        float hp  = hprev[JT_][i]; \
        hprev[JT_][i] = fmaf(uu, nn - hp, hp); \
    } \
    uint2 hq; \
    hq.x = pkbf(hprev[JT_][0], hprev[JT_][1]); \
    hq.y = pkbf(hprev[JT_][2], hprev[JT_][3]); \
    *(uint2*)(hwp + ((JT_) * 512 + (1 - (P_)) * 8192)) = hq; \
    float4 st = { hprev[JT_][0], hprev[JT_][1], hprev[JT_][2], hprev[JT_][3] }; \
    *(float4*)(op + (JT_) * 64) = st; \
    } while (0)

#define BODY(T_, P_) do { \
    f32x4 acc0 = { bflo(xq0.x), bfhi(xq0.x), bflo(xq0.y), bfhi(xq0.y) }; \
    f32x4 acc1 = { bflo(xq0.z), bfhi(xq0.z), bflo(xq0.w), bfhi(xq0.w) }; \
    f32x4 acc2 = { bflo(xq1.x), bfhi(xq1.x), bflo(xq1.y), bfhi(xq1.y) }; \
    f32x4 acc3 = { bflo(xq1.z), bfhi(xq1.z), bflo(xq1.w), bfhi(xq1.w) }; \
    f32x4 acc4 = { bflo(bHnP[0].x), bfhi(bHnP[0].x), bflo(bHnP[0].y), bfhi(bHnP[0].y) }; \
    f32x4 acc5 = { bflo(bHnP[1].x), bfhi(bHnP[1].x), bflo(bHnP[1].y), bfhi(bHnP[1].y) }; \
    xq0 = *(const uint4*)(xqn + 0); \
    xq1 = *(const uint4*)(xqn + 16); \
    _Pragma("unroll") for (int kk = 0; kk < 8; ++kk) { \
        bf16x8 h_ = *(const bf16x8*)(hrp + (kk * 1024 + (P_) * 8192)); \
        acc0 = __builtin_amdgcn_mfma_f32_16x16x32_bf16(wf[0][kk], h_, acc0, 0, 0, 0); \
        acc1 = __builtin_amdgcn_mfma_f32_16x16x32_bf16(wf[1][kk], h_, acc1, 0, 0, 0); \
        acc2 = __builtin_amdgcn_mfma_f32_16x16x32_bf16(wf[2][kk], h_, acc2, 0, 0, 0); \
        acc3 = __builtin_amdgcn_mfma_f32_16x16x32_bf16(wf[3][kk], h_, acc3, 0, 0, 0); \
        acc4 = __builtin_amdgcn_mfma_f32_16x16x32_bf16(wf[4][kk], h_, acc4, 0, 0, 0); \
        acc5 = __builtin_amdgcn_mfma_f32_16x16x32_bf16(wf[5][kk], h_, acc5, 0, 0, 0); \
    } \
    GATES(P_, 0, acc0, acc2, acc4, xq2.x, xq2.y); \
    GATES(P_, 1, acc1, acc3, acc5, xq2.z, xq2.w); \
    xq2 = *(const uint4*)(xqn + 32); \
    if ((T_) + 2 < SEQ) xqn += SLAB; \
    op += 1024; \
    __builtin_amdgcn_sched_barrier(0); \
    asm volatile("s_waitcnt lgkmcnt(0)" ::: "memory"); \
    __builtin_amdgcn_s_barrier(); \
    __builtin_amdgcn_sched_barrier(0); \
} while (0)

    for (int tt = 0; tt < SEQ; tt += 2) {
        BODY(tt + 0, 0);
        BODY(tt + 1, 1);
    }
#undef BODY
#undef GATES
}

extern "C" void kernel_launch(void* const* d_in, const int* in_sizes, int n_in,
                              void* d_out, int out_size, void* d_ws, size_t ws_size,
                              hipStream_t stream) {
    const float* x    = (const float*)d_in[0];
    const float* h0   = (const float*)d_in[1];
    const float* w_ih = (const float*)d_in[2];
    const float* w_hh = (const float*)d_in[3];
    const float* b_ih = (const float*)d_in[4];
    const float* b_hh = (const float*)d_in[5];
    float* out = (float*)d_out;
    char* xg = (char*)d_ws;   // needs SEQ*49152 = 192 MB

    (void)in_sizes; (void)n_in; (void)out_size; (void)ws_size;

    gru_xproj<<<dim3(SEQ / 32, 2), dim3(512), 0, stream>>>(x, w_ih, b_ih, b_hh, xg);
    gru_rec<<<dim3(2), dim3(512), 0, stream>>>(w_hh, b_hh, h0, xg, out);
}

// Round 9
// 5601.231 us; speedup vs baseline: 1.6477x; 1.6477x over previous
//
#include <hip/hip_runtime.h>
#include <hip/hip_bf16.h>

#define SEQ    4096
// xg layout: [t][blk(4)][wave(8)][l4(4)][bl(8)][48B]; per consumer thread
// r/z/n uint4 at +0/+16/+32; within gate: jt0 8B, jt1 8B (4 bf16 j-values).
// slab = 4*12288 = 49152 B per t (192 MB total).
#define SLAB   49152

typedef __attribute__((ext_vector_type(8))) short bf16x8;
typedef __attribute__((ext_vector_type(4))) float f32x4;

__device__ __forceinline__ unsigned int pkbf(float a, float b) {
    __hip_bfloat162 h = __float22bfloat162_rn(make_float2(a, b));
    union { __hip_bfloat162 h2; unsigned int u; } c; c.h2 = h; return c.u;
}
__device__ __forceinline__ float bflo(unsigned int q) { return __uint_as_float(q << 16); }
__device__ __forceinline__ float bfhi(unsigned int q) { return __uint_as_float(q & 0xFFFF0000u); }

// ---------------------------------------------------------------------------
// Kernel B: x_proj = x @ W_ih^T (scaled, bias-folded), bf16, operand-swapped:
// A = W_ih (gate rows), B = x^T (batch cols) -> C[gate j][batch].
// Stores into the 4-consumer-block layout. grid (SEQ/32, 2), block 512.
// ---------------------------------------------------------------------------
__global__ __launch_bounds__(512, 2) void gru_xproj(
    const float* __restrict__ x, const float* __restrict__ w_ih,
    const float* __restrict__ b_ih, const float* __restrict__ b_hh,
    char* __restrict__ xg)
{
    __shared__ __align__(16) char xlds[2][16384];
    const int tid = threadIdx.x;
    const int lane = tid & 63, wave = tid >> 6;
    const int l15 = lane & 15, l4 = lane >> 4;
    const int t0 = blockIdx.x * 32;
    const int gw0 = blockIdx.y * 384 + wave * 48;

    bf16x8 wa[3][8];
    float bias[3][4];
    int coffA[3];      // pg[gt] + (l15&7)*48
    #pragma unroll
    for (int gt = 0; gt < 3; ++gt) {
        const int T = gw0 + gt * 16;
        const float s = (T < 256) ? -1.442695041f : ((T < 512) ? 1.442695041f : 2.885390082f);
        const int row = T + l15;
        #pragma unroll
        for (int kk = 0; kk < 8; ++kk) {
            const float* p = w_ih + row * 256 + kk * 32 + l4 * 8;
            float4 aa = *(const float4*)p;
            float4 bb = *(const float4*)(p + 4);
            union { bf16x8 v; unsigned int u[4]; } f;
            f.u[0] = pkbf(s * aa.x, s * aa.y); f.u[1] = pkbf(s * aa.z, s * aa.w);
            f.u[2] = pkbf(s * bb.x, s * bb.y); f.u[3] = pkbf(s * bb.z, s * bb.w);
            wa[gt][kk] = f.v;
        }
        #pragma unroll
        for (int q = 0; q < 4; ++q) {
            const int g = T + 4 * l4 + q;
            bias[gt][q] = (g < 512) ? s * (b_ih[g] + b_hh[g]) : s * b_ih[g];
        }
        const int gi  = T >> 8;                 // gate index r/z/n
        const int jg  = (T & 255) + 4 * l4;     // j within gate (mult of 4)
        const int wc  = jg >> 5;                // consumer wave
        const int jt  = (jg >> 4) & 1;
        const int l4c = (jg >> 2) & 3;
        coffA[gt] = wc * 1536 + l4c * 384 + (l15 & 7) * 48 + gi * 16 + jt * 8;
    }
    const int blkpart0 = (0 * 2 + (l15 >> 3)) * 12288;   // bt = 0
    const int blkpart1 = (1 * 2 + (l15 >> 3)) * 12288;   // bt = 1

    for (int tt = 0; tt < 32; ++tt) {
        const int t = t0 + tt;
        const int buf = tt & 1;
        {
            const int b  = tid >> 4;
            const int k0 = (tid & 15) * 16;
            const float* xp = x + ((size_t)b * SEQ + t) * 256 + k0;
            float4 u0 = *(const float4*)(xp + 0);
            float4 u1 = *(const float4*)(xp + 4);
            float4 u2 = *(const float4*)(xp + 8);
            float4 u3 = *(const float4*)(xp + 12);
            union { bf16x8 v; unsigned int u[4]; } w0, w1;
            w0.u[0] = pkbf(u0.x,u0.y); w0.u[1] = pkbf(u0.z,u0.w);
            w0.u[2] = pkbf(u1.x,u1.y); w0.u[3] = pkbf(u1.z,u1.w);
            w1.u[0] = pkbf(u2.x,u2.y); w1.u[1] = pkbf(u2.z,u2.w);
            w1.u[2] = pkbf(u3.x,u3.y); w1.u[3] = pkbf(u3.z,u3.w);
            const int a0 = (b >> 4) * 8192 + (k0 >> 5) * 1024 + ((k0 >> 3) & 3) * 256 + (b & 15) * 16;
            *(bf16x8*)(xlds[buf] + a0      ) = w0.v;
            *(bf16x8*)(xlds[buf] + a0 + 256) = w1.v;
        }
        __syncthreads();

        f32x4 acc[3][2];
        #pragma unroll
        for (int gt = 0; gt < 3; ++gt)
            #pragma unroll
            for (int bt = 0; bt < 2; ++bt)
                acc[gt][bt] = (f32x4){bias[gt][0], bias[gt][1], bias[gt][2], bias[gt][3]};

        #pragma unroll
        for (int kk = 0; kk < 8; ++kk) {
            bf16x8 b0 = *(const bf16x8*)(xlds[buf] + (       kk * 1024 + l4 * 256 + l15 * 16));
            bf16x8 b1 = *(const bf16x8*)(xlds[buf] + (8192 + kk * 1024 + l4 * 256 + l15 * 16));
            #pragma unroll
            for (int gt = 0; gt < 3; ++gt) {
                acc[gt][0] = __builtin_amdgcn_mfma_f32_16x16x32_bf16(wa[gt][kk], b0, acc[gt][0], 0, 0, 0);
                acc[gt][1] = __builtin_amdgcn_mfma_f32_16x16x32_bf16(wa[gt][kk], b1, acc[gt][1], 0, 0, 0);
            }
        }
        #pragma unroll
        for (int bt = 0; bt < 2; ++bt)
            #pragma unroll
            for (int gt = 0; gt < 3; ++gt) {
                uint2 q;
                q.x = pkbf(acc[gt][bt][0], acc[gt][bt][1]);
                q.y = pkbf(acc[gt][bt][2], acc[gt][bt][3]);
                *(uint2*)(xg + (size_t)t * SLAB + (bt ? blkpart1 : blkpart0) + coffA[gt]) = q;
            }
    }
}

// ---------------------------------------------------------------------------
// Kernel C: persistent GRU scan, operand-swapped, batch-split. grid(4):
// block b owns batches [8b, 8b+8). 8 waves; wave w owns hidden cols
// [32w,32w+32) x 3 gates. 5 weight tiles in regs (160); n-gate jt1 tile in
// LDS (per-wave, imm-offset). h double-buffered bf16 in LDS, 8-batch tile:
// [buf][kk(8)][slot(4)][b(8)][16B] -> B-operand reads are 2-lane broadcast.
// Lanes l15>=8 alias batch l15&7 (garbage compute, predicated stores).
// LDS: hb 8KB + wn 64KB = 72KB dynamic. Raw s_barrier + lgkmcnt(0) only.
// ---------------------------------------------------------------------------
__global__ __launch_bounds__(512, 2) void gru_rec(
    const float* __restrict__ w_hh, const float* __restrict__ b_hh,
    const float* __restrict__ h0, const char* __restrict__ xg,
    float* __restrict__ out)
{
    extern __shared__ __align__(16) char smem[];
    char* hb = smem;           // [2][4096]
    char* wn = smem + 8192;    // [wave(8)][kk(8)][1KB] = 64KB
    const int tid = threadIdx.x, lane = tid & 63, wave = tid >> 6;
    const int l15 = lane & 15, l4 = lane >> 4;
    const int bl  = l15 & 7;             // aliased batch lane
    const bool vld = (l15 < 8);
    const int blk = blockIdx.x;
    const int j0 = wave * 32;

    // tiles g6=0..4 in regs (160); g6=5 (n-gate jt1) -> LDS
    bf16x8 wf[5][8];
    #pragma unroll
    for (int g6 = 0; g6 < 6; ++g6) {
        const int gate = g6 >> 1, jt = g6 & 1;
        const int row = gate * 256 + j0 + jt * 16 + l15;
        const float s = (gate == 0) ? -1.442695041f : ((gate == 1) ? 1.442695041f : 2.885390082f);
        #pragma unroll
        for (int kk = 0; kk < 8; ++kk) {
            const float* p = w_hh + row * 256 + kk * 32 + l4 * 8;
            float4 aa = *(const float4*)p;
            float4 bb = *(const float4*)(p + 4);
            union { bf16x8 v; unsigned int u[4]; } f;
            f.u[0] = pkbf(s * aa.x, s * aa.y); f.u[1] = pkbf(s * aa.z, s * aa.w);
            f.u[2] = pkbf(s * bb.x, s * bb.y); f.u[3] = pkbf(s * bb.z, s * bb.w);
            if (g6 < 5) wf[g6][kk] = f.v;
            else *(bf16x8*)(wn + ((wave * 8 + kk) * 1024 + lane * 16)) = f.v;
        }
    }
    // n-gate b_hh, scaled, packed bf16
    uint2 bHnP[2];
    #pragma unroll
    for (int jt = 0; jt < 2; ++jt) {
        const int j = j0 + jt * 16 + 4 * l4;
        bHnP[jt].x = pkbf(2.885390082f * b_hh[512 + j + 0], 2.885390082f * b_hh[512 + j + 1]);
        bHnP[jt].y = pkbf(2.885390082f * b_hh[512 + j + 2], 2.885390082f * b_hh[512 + j + 3]);
    }

    // LDS bases (per-step offsets are compile-time immediates)
    char* hwp = hb + (wave * 512 + (l4 >> 1) * 128 + (l4 & 1) * 8 + bl * 16);
    const char* hrp = hb + (l4 * 128 + bl * 16);
    const char* wnp = wn + (wave * 8192 + lane * 16);

    // initial h (aliased loads; predicated LDS writes)
    float hprev[2][4];
    #pragma unroll
    for (int jt = 0; jt < 2; ++jt) {
        const float* hp0 = h0 + (blk * 8 + bl) * 256 + j0 + jt * 16 + 4 * l4;
        float4 h4 = *(const float4*)hp0;
        hprev[jt][0] = h4.x; hprev[jt][1] = h4.y; hprev[jt][2] = h4.z; hprev[jt][3] = h4.w;
        if (vld) {
            uint2 hq;
            hq.x = pkbf(h4.x, h4.y); hq.y = pkbf(h4.z, h4.w);
            *(uint2*)(hwp + jt * 256) = hq;
        }
    }

    const char* xqb = xg + blk * 12288 + wave * 1536 + l4 * 384 + bl * 48;
    char* op = (char*)out + ((size_t)(blk * 8 + l15) * SEQ * 256 + j0 + 4 * l4) * 4;

    // distance-1 prefetch: single slot (12 regs)
    uint4 xq0 = *(const uint4*)(xqb + 0);
    uint4 xq1 = *(const uint4*)(xqb + 16);
    uint4 xq2 = *(const uint4*)(xqb + 32);
    const char* xqn = xqb + SLAB;

    asm volatile("s_waitcnt lgkmcnt(0)" ::: "memory");
    __builtin_amdgcn_s_barrier();
    __builtin_amdgcn_sched_barrier(0);

#define GATES(P_, JT_, AR, AZ, AN, QX, QY) do { \
    float xn[4] = { bflo(QX), bfhi(QX), bflo(QY), bfhi(QY) }; \
    _Pragma("unroll") for (int i = 0; i < 4; ++i) { \
        float r   = __builtin_amdgcn_rcpf(1.0f + __builtin_amdgcn_exp2f(AR[i])); \
        float uu  = __builtin_amdgcn_rcpf(1.0f + __builtin_amdgcn_exp2f(AZ[i])); \
        float pre = fmaf(r, AN[i], xn[i]); \
        float nn  = fmaf(-2.0f, __builtin_amdgcn_rcpf(1.0f + __builtin_amdgcn_exp2f(pre)), 1.0f); \
        float hp  = hprev[JT_][i]; \
        hprev[JT_][i] = fmaf(uu, nn - hp, hp); \
    } \
    if (vld) { \
        uint2 hq; \
        hq.x = pkbf(hprev[JT_][0], hprev[JT_][1]); \
        hq.y = pkbf(hprev[JT_][2], hprev[JT_][3]); \
        *(uint2*)(hwp + ((JT_) * 256 + (1 - (P_)) * 4096)) = hq; \
        float4 st = { hprev[JT_][0], hprev[JT_][1], hprev[JT_][2], hprev[JT_][3] }; \
        *(float4*)(op + (JT_) * 64) = st; \
    } } while (0)

#define BODY(T_, P_) do { \
    f32x4 acc0 = { bflo(xq0.x), bfhi(xq0.x), bflo(xq0.y), bfhi(xq0.y) }; \
    f32x4 acc1 = { bflo(xq0.z), bfhi(xq0.z), bflo(xq0.w), bfhi(xq0.w) }; \
    f32x4 acc2 = { bflo(xq1.x), bfhi(xq1.x), bflo(xq1.y), bfhi(xq1.y) }; \
    f32x4 acc3 = { bflo(xq1.z), bfhi(xq1.z), bflo(xq1.w), bfhi(xq1.w) }; \
    f32x4 acc4 = { bflo(bHnP[0].x), bfhi(bHnP[0].x), bflo(bHnP[0].y), bfhi(bHnP[0].y) }; \
    f32x4 acc5 = { bflo(bHnP[1].x), bfhi(bHnP[1].x), bflo(bHnP[1].y), bfhi(bHnP[1].y) }; \
    xq0 = *(const uint4*)(xqn + 0); \
    xq1 = *(const uint4*)(xqn + 16); \
    _Pragma("unroll") for (int kk = 0; kk < 8; ++kk) { \
        bf16x8 h_ = *(const bf16x8*)(hrp + (kk * 512 + (P_) * 4096)); \
        bf16x8 w5 = *(const bf16x8*)(wnp + (kk * 1024)); \
        acc0 = __builtin_amdgcn_mfma_f32_16x16x32_bf16(wf[0][kk], h_, acc0, 0, 0, 0); \
        acc1 = __builtin_amdgcn_mfma_f32_16x16x32_bf16(wf[1][kk], h_, acc1, 0, 0, 0); \
        acc2 = __builtin_amdgcn_mfma_f32_16x16x32_bf16(wf[2][kk], h_, acc2, 0, 0, 0); \
        acc3 = __builtin_amdgcn_mfma_f32_16x16x32_bf16(wf[3][kk], h_, acc3, 0, 0, 0); \
        acc4 = __builtin_amdgcn_mfma_f32_16x16x32_bf16(wf[4][kk], h_, acc4, 0, 0, 0); \
        acc5 = __builtin_amdgcn_mfma_f32_16x16x32_bf16(w5, h_, acc5, 0, 0, 0); \
    } \
    GATES(P_, 0, acc0, acc2, acc4, xq2.x, xq2.y); \
    GATES(P_, 1, acc1, acc3, acc5, xq2.z, xq2.w); \
    xq2 = *(const uint4*)(xqn + 32); \
    if ((T_) + 2 < SEQ) xqn += SLAB; \
    op += 1024; \
    __builtin_amdgcn_sched_barrier(0); \
    asm volatile("s_waitcnt lgkmcnt(0)" ::: "memory"); \
    __builtin_amdgcn_s_barrier(); \
    __builtin_amdgcn_sched_barrier(0); \
} while (0)

    for (int tt = 0; tt < SEQ; tt += 2) {
        BODY(tt + 0, 0);
        BODY(tt + 1, 1);
    }
#undef BODY
#undef GATES
}

extern "C" void kernel_launch(void* const* d_in, const int* in_sizes, int n_in,
                              void* d_out, int out_size, void* d_ws, size_t ws_size,
                              hipStream_t stream) {
    const float* x    = (const float*)d_in[0];
    const float* h0   = (const float*)d_in[1];
    const float* w_ih = (const float*)d_in[2];
    const float* w_hh = (const float*)d_in[3];
    const float* b_ih = (const float*)d_in[4];
    const float* b_hh = (const float*)d_in[5];
    float* out = (float*)d_out;
    char* xg = (char*)d_ws;   // needs SEQ*49152 = 192 MB

    (void)in_sizes; (void)n_in; (void)out_size; (void)ws_size;

    hipFuncSetAttribute((const void*)gru_rec,
                        hipFuncAttributeMaxDynamicSharedMemorySize, 73728);

    gru_xproj<<<dim3(SEQ / 32, 2), dim3(512), 0, stream>>>(x, w_ih, b_ih, b_hh, xg);
    gru_rec<<<dim3(4), dim3(512), 73728, stream>>>(w_hh, b_hh, h0, xg, out);
}

// Round 10
// 5210.669 us; speedup vs baseline: 1.7712x; 1.0750x over previous
//
#include <hip/hip_runtime.h>
#include <hip/hip_bf16.h>

#define SEQ    4096
// xg layout: [t][blk(4)][wave(8)][l4(4)][bl(8)][48B]; per consumer thread
// r/z/n uint4 at +0/+16/+32; within gate: jt0 8B, jt1 8B (4 bf16 j-values).
// slab = 4*12288 = 49152 B per t (192 MB total).
#define SLAB   49152

typedef __attribute__((ext_vector_type(8))) short bf16x8;
typedef __attribute__((ext_vector_type(4))) float f32x4;

__device__ __forceinline__ unsigned int pkbf(float a, float b) {
    __hip_bfloat162 h = __float22bfloat162_rn(make_float2(a, b));
    union { __hip_bfloat162 h2; unsigned int u; } c; c.h2 = h; return c.u;
}
__device__ __forceinline__ float bflo(unsigned int q) { return __uint_as_float(q << 16); }
__device__ __forceinline__ float bfhi(unsigned int q) { return __uint_as_float(q & 0xFFFF0000u); }

// ---------------------------------------------------------------------------
// Kernel B: x_proj = x @ W_ih^T (scaled, bias-folded), bf16, operand-swapped:
// A = W_ih (gate rows), B = x^T (batch cols) -> C[gate j][batch].
// Stores into the 4-consumer-block layout. grid (SEQ/32, 2), block 512.
// (unchanged from round 9 — verified)
// ---------------------------------------------------------------------------
__global__ __launch_bounds__(512, 2) void gru_xproj(
    const float* __restrict__ x, const float* __restrict__ w_ih,
    const float* __restrict__ b_ih, const float* __restrict__ b_hh,
    char* __restrict__ xg)
{
    __shared__ __align__(16) char xlds[2][16384];
    const int tid = threadIdx.x;
    const int lane = tid & 63, wave = tid >> 6;
    const int l15 = lane & 15, l4 = lane >> 4;
    const int t0 = blockIdx.x * 32;
    const int gw0 = blockIdx.y * 384 + wave * 48;

    bf16x8 wa[3][8];
    float bias[3][4];
    int coffA[3];
    #pragma unroll
    for (int gt = 0; gt < 3; ++gt) {
        const int T = gw0 + gt * 16;
        const float s = (T < 256) ? -1.442695041f : ((T < 512) ? 1.442695041f : 2.885390082f);
        const int row = T + l15;
        #pragma unroll
        for (int kk = 0; kk < 8; ++kk) {
            const float* p = w_ih + row * 256 + kk * 32 + l4 * 8;
            float4 aa = *(const float4*)p;
            float4 bb = *(const float4*)(p + 4);
            union { bf16x8 v; unsigned int u[4]; } f;
            f.u[0] = pkbf(s * aa.x, s * aa.y); f.u[1] = pkbf(s * aa.z, s * aa.w);
            f.u[2] = pkbf(s * bb.x, s * bb.y); f.u[3] = pkbf(s * bb.z, s * bb.w);
            wa[gt][kk] = f.v;
        }
        #pragma unroll
        for (int q = 0; q < 4; ++q) {
            const int g = T + 4 * l4 + q;
            bias[gt][q] = (g < 512) ? s * (b_ih[g] + b_hh[g]) : s * b_ih[g];
        }
        const int gi  = T >> 8;
        const int jg  = (T & 255) + 4 * l4;
        const int wc  = jg >> 5;
        const int jt  = (jg >> 4) & 1;
        const int l4c = (jg >> 2) & 3;
        coffA[gt] = wc * 1536 + l4c * 384 + (l15 & 7) * 48 + gi * 16 + jt * 8;
    }
    const int blkpart0 = (0 * 2 + (l15 >> 3)) * 12288;
    const int blkpart1 = (1 * 2 + (l15 >> 3)) * 12288;

    for (int tt = 0; tt < 32; ++tt) {
        const int t = t0 + tt;
        const int buf = tt & 1;
        {
            const int b  = tid >> 4;
            const int k0 = (tid & 15) * 16;
            const float* xp = x + ((size_t)b * SEQ + t) * 256 + k0;
            float4 u0 = *(const float4*)(xp + 0);
            float4 u1 = *(const float4*)(xp + 4);
            float4 u2 = *(const float4*)(xp + 8);
            float4 u3 = *(const float4*)(xp + 12);
            union { bf16x8 v; unsigned int u[4]; } w0, w1;
            w0.u[0] = pkbf(u0.x,u0.y); w0.u[1] = pkbf(u0.z,u0.w);
            w0.u[2] = pkbf(u1.x,u1.y); w0.u[3] = pkbf(u1.z,u1.w);
            w1.u[0] = pkbf(u2.x,u2.y); w1.u[1] = pkbf(u2.z,u2.w);
            w1.u[2] = pkbf(u3.x,u3.y); w1.u[3] = pkbf(u3.z,u3.w);
            const int a0 = (b >> 4) * 8192 + (k0 >> 5) * 1024 + ((k0 >> 3) & 3) * 256 + (b & 15) * 16;
            *(bf16x8*)(xlds[buf] + a0      ) = w0.v;
            *(bf16x8*)(xlds[buf] + a0 + 256) = w1.v;
        }
        __syncthreads();

        f32x4 acc[3][2];
        #pragma unroll
        for (int gt = 0; gt < 3; ++gt)
            #pragma unroll
            for (int bt = 0; bt < 2; ++bt)
                acc[gt][bt] = (f32x4){bias[gt][0], bias[gt][1], bias[gt][2], bias[gt][3]};

        #pragma unroll
        for (int kk = 0; kk < 8; ++kk) {
            bf16x8 b0 = *(const bf16x8*)(xlds[buf] + (       kk * 1024 + l4 * 256 + l15 * 16));
            bf16x8 b1 = *(const bf16x8*)(xlds[buf] + (8192 + kk * 1024 + l4 * 256 + l15 * 16));
            #pragma unroll
            for (int gt = 0; gt < 3; ++gt) {
                acc[gt][0] = __builtin_amdgcn_mfma_f32_16x16x32_bf16(wa[gt][kk], b0, acc[gt][0], 0, 0, 0);
                acc[gt][1] = __builtin_amdgcn_mfma_f32_16x16x32_bf16(wa[gt][kk], b1, acc[gt][1], 0, 0, 0);
            }
        }
        #pragma unroll
        for (int bt = 0; bt < 2; ++bt)
            #pragma unroll
            for (int gt = 0; gt < 3; ++gt) {
                uint2 q;
                q.x = pkbf(acc[gt][bt][0], acc[gt][bt][1]);
                q.y = pkbf(acc[gt][bt][2], acc[gt][bt][3]);
                *(uint2*)(xg + (size_t)t * SLAB + (bt ? blkpart1 : blkpart0) + coffA[gt]) = q;
            }
    }
}

// ---------------------------------------------------------------------------
// Kernel C: persistent GRU scan, operand-swapped, batch-split, jt-split GATES.
// grid(4): block b owns batches [8b, 8b+8). 8 waves; wave w: hidden cols
// [32w,32w+32) x 3 gates. 5 weight tiles in regs; n-gate jt1 tile in LDS.
// h double-buffered bf16 in LDS (broadcast reads, conflict-free).
// Lane pairs (l15, l15+8) hold duplicate accs -> lanes l15<8 run GATES for
// jt0, lanes l15>=8 for jt1 (v_cndmask select). Trans/thread halves: 48->24.
// All stores full-lane, unpredicated. LDS: hb 8KB + wn 64KB = 72KB dynamic.
// ---------------------------------------------------------------------------
__global__ __launch_bounds__(512, 2) void gru_rec(
    const float* __restrict__ w_hh, const float* __restrict__ b_hh,
    const float* __restrict__ h0, const char* __restrict__ xg,
    float* __restrict__ out)
{
    extern __shared__ __align__(16) char smem[];
    char* hb = smem;           // [2][4096]
    char* wn = smem + 8192;    // [wave(8)][kk(8)][1KB] = 64KB
    const int tid = threadIdx.x, lane = tid & 63, wave = tid >> 6;
    const int l15 = lane & 15, l4 = lane >> 4;
    const int bl  = l15 & 7;             // batch lane
    const int jtl = l15 >> 3;            // this lane's jt assignment
    const bool lo = (l15 < 8);
    const int blk = blockIdx.x;
    const int j0 = wave * 32;

    // tiles g6=0..4 in regs (160); g6=5 (n-gate jt1) -> LDS
    bf16x8 wf[5][8];
    #pragma unroll
    for (int g6 = 0; g6 < 6; ++g6) {
        const int gate = g6 >> 1, jt = g6 & 1;
        const int row = gate * 256 + j0 + jt * 16 + l15;
        const float s = (gate == 0) ? -1.442695041f : ((gate == 1) ? 1.442695041f : 2.885390082f);
        #pragma unroll
        for (int kk = 0; kk < 8; ++kk) {
            const float* p = w_hh + row * 256 + kk * 32 + l4 * 8;
            float4 aa = *(const float4*)p;
            float4 bb = *(const float4*)(p + 4);
            union { bf16x8 v; unsigned int u[4]; } f;
            f.u[0] = pkbf(s * aa.x, s * aa.y); f.u[1] = pkbf(s * aa.z, s * aa.w);
            f.u[2] = pkbf(s * bb.x, s * bb.y); f.u[3] = pkbf(s * bb.z, s * bb.w);
            if (g6 < 5) wf[g6][kk] = f.v;
            else *(bf16x8*)(wn + ((wave * 8 + kk) * 1024 + lane * 16)) = f.v;
        }
    }
    // n-gate b_hh, scaled, packed bf16 (both jt halves needed for MFMA C-init)
    uint2 bHnP[2];
    #pragma unroll
    for (int jt = 0; jt < 2; ++jt) {
        const int j = j0 + jt * 16 + 4 * l4;
        bHnP[jt].x = pkbf(2.885390082f * b_hh[512 + j + 0], 2.885390082f * b_hh[512 + j + 1]);
        bHnP[jt].y = pkbf(2.885390082f * b_hh[512 + j + 2], 2.885390082f * b_hh[512 + j + 3]);
    }

    // LDS bases (per-step offsets are compile-time immediates)
    char* hwp = hb + (wave * 512 + jtl * 256 + (l4 >> 1) * 128 + (l4 & 1) * 8 + bl * 16);
    const char* hrp = hb + (l4 * 128 + bl * 16);
    const char* wnp = wn + (wave * 8192 + lane * 16);

    // initial h: each lane owns (batch=bl, j = j0 + jtl*16 + 4*l4 + {0..3})
    float hprev[4];
    {
        const float* hp0 = h0 + (blk * 8 + bl) * 256 + j0 + jtl * 16 + 4 * l4;
        float4 h4 = *(const float4*)hp0;
        hprev[0] = h4.x; hprev[1] = h4.y; hprev[2] = h4.z; hprev[3] = h4.w;
        uint2 hq;
        hq.x = pkbf(h4.x, h4.y); hq.y = pkbf(h4.z, h4.w);
        *(uint2*)hwp = hq;
    }

    const char* xqb = xg + blk * 12288 + wave * 1536 + l4 * 384 + bl * 48;
    char* op = (char*)out + ((size_t)(blk * 8 + bl) * SEQ * 256 + j0 + jtl * 16 + 4 * l4) * 4;

    // distance-1 prefetch: single slot (12 regs)
    uint4 xq0 = *(const uint4*)(xqb + 0);
    uint4 xq1 = *(const uint4*)(xqb + 16);
    uint4 xq2 = *(const uint4*)(xqb + 32);
    const char* xqn = xqb + SLAB;

    asm volatile("s_waitcnt lgkmcnt(0)" ::: "memory");
    __builtin_amdgcn_s_barrier();
    __builtin_amdgcn_sched_barrier(0);

#define BODY(T_, P_) do { \
    f32x4 acc0 = { bflo(xq0.x), bfhi(xq0.x), bflo(xq0.y), bfhi(xq0.y) }; \
    f32x4 acc1 = { bflo(xq0.z), bfhi(xq0.z), bflo(xq0.w), bfhi(xq0.w) }; \
    f32x4 acc2 = { bflo(xq1.x), bfhi(xq1.x), bflo(xq1.y), bfhi(xq1.y) }; \
    f32x4 acc3 = { bflo(xq1.z), bfhi(xq1.z), bflo(xq1.w), bfhi(xq1.w) }; \
    f32x4 acc4 = { bflo(bHnP[0].x), bfhi(bHnP[0].x), bflo(bHnP[0].y), bfhi(bHnP[0].y) }; \
    f32x4 acc5 = { bflo(bHnP[1].x), bfhi(bHnP[1].x), bflo(bHnP[1].y), bfhi(bHnP[1].y) }; \
    xq0 = *(const uint4*)(xqn + 0); \
    xq1 = *(const uint4*)(xqn + 16); \
    _Pragma("unroll") for (int kk = 0; kk < 8; ++kk) { \
        bf16x8 h_ = *(const bf16x8*)(hrp + (kk * 512 + (P_) * 4096)); \
        bf16x8 w5 = *(const bf16x8*)(wnp + (kk * 1024)); \
        acc0 = __builtin_amdgcn_mfma_f32_16x16x32_bf16(wf[0][kk], h_, acc0, 0, 0, 0); \
        acc1 = __builtin_amdgcn_mfma_f32_16x16x32_bf16(wf[1][kk], h_, acc1, 0, 0, 0); \
        acc2 = __builtin_amdgcn_mfma_f32_16x16x32_bf16(wf[2][kk], h_, acc2, 0, 0, 0); \
        acc3 = __builtin_amdgcn_mfma_f32_16x16x32_bf16(wf[3][kk], h_, acc3, 0, 0, 0); \
        acc4 = __builtin_amdgcn_mfma_f32_16x16x32_bf16(wf[4][kk], h_, acc4, 0, 0, 0); \
        acc5 = __builtin_amdgcn_mfma_f32_16x16x32_bf16(w5, h_, acc5, 0, 0, 0); \
    } \
    const unsigned qx = lo ? xq2.x : xq2.z; \
    const unsigned qy = lo ? xq2.y : xq2.w; \
    float xn[4] = { bflo(qx), bfhi(qx), bflo(qy), bfhi(qy) }; \
    _Pragma("unroll") for (int i = 0; i < 4; ++i) { \
        float ar = lo ? acc0[i] : acc1[i]; \
        float az = lo ? acc2[i] : acc3[i]; \
        float an = lo ? acc4[i] : acc5[i]; \
        float r   = __builtin_amdgcn_rcpf(1.0f + __builtin_amdgcn_exp2f(ar)); \
        float uu  = __builtin_amdgcn_rcpf(1.0f + __builtin_amdgcn_exp2f(az)); \
        float pre = fmaf(r, an, xn[i]); \
        float nn  = fmaf(-2.0f, __builtin_amdgcn_rcpf(1.0f + __builtin_amdgcn_exp2f(pre)), 1.0f); \
        float hp  = hprev[i]; \
        hprev[i] = fmaf(uu, nn - hp, hp); \
    } \
    { \
        uint2 hq; \
        hq.x = pkbf(hprev[0], hprev[1]); \
        hq.y = pkbf(hprev[2], hprev[3]); \
        *(uint2*)(hwp + (1 - (P_)) * 4096) = hq; \
        float4 st = { hprev[0], hprev[1], hprev[2], hprev[3] }; \
        *(float4*)op = st; \
    } \
    xq2 = *(const uint4*)(xqn + 32); \
    if ((T_) + 2 < SEQ) xqn += SLAB; \
    op += 1024; \
    __builtin_amdgcn_sched_barrier(0); \
    asm volatile("s_waitcnt lgkmcnt(0)" ::: "memory"); \
    __builtin_amdgcn_s_barrier(); \
    __builtin_amdgcn_sched_barrier(0); \
} while (0)

    for (int tt = 0; tt < SEQ; tt += 2) {
        BODY(tt + 0, 0);
        BODY(tt + 1, 1);
    }
#undef BODY
}

extern "C" void kernel_launch(void* const* d_in, const int* in_sizes, int n_in,
                              void* d_out, int out_size, void* d_ws, size_t ws_size,
                              hipStream_t stream) {
    const float* x    = (const float*)d_in[0];
    const float* h0   = (const float*)d_in[1];
    const float* w_ih = (const float*)d_in[2];
    const float* w_hh = (const float*)d_in[3];
    const float* b_ih = (const float*)d_in[4];
    const float* b_hh = (const float*)d_in[5];
    float* out = (float*)d_out;
    char* xg = (char*)d_ws;   // needs SEQ*49152 = 192 MB

    (void)in_sizes; (void)n_in; (void)out_size; (void)ws_size;

    hipFuncSetAttribute((const void*)gru_rec,
                        hipFuncAttributeMaxDynamicSharedMemorySize, 73728);

    gru_xproj<<<dim3(SEQ / 32, 2), dim3(512), 0, stream>>>(x, w_ih, b_ih, b_hh, xg);
    gru_rec<<<dim3(4), dim3(512), 73728, stream>>>(w_hh, b_hh, h0, xg, out);
}

// Round 11
// 4610.020 us; speedup vs baseline: 2.0020x; 1.1303x over previous
//
#include <hip/hip_runtime.h>
#include <hip/hip_bf16.h>

#define SEQ    4096
// xg layout: [t][blk(8)][wave(8)][l4(4)][bl(4)][48B]; per consumer group
// r/z/n uint4 at +0/+16/+32; within gate: jt0 8B, jt1 8B (4 bf16 j-values).
// slab = 8*6144 = 49152 B per t (192 MB total).
#define SLAB   49152

typedef __attribute__((ext_vector_type(8))) short bf16x8;
typedef __attribute__((ext_vector_type(4))) float f32x4;

__device__ __forceinline__ unsigned int pkbf(float a, float b) {
    __hip_bfloat162 h = __float22bfloat162_rn(make_float2(a, b));
    union { __hip_bfloat162 h2; unsigned int u; } c; c.h2 = h; return c.u;
}
__device__ __forceinline__ float bflo(unsigned int q) { return __uint_as_float(q << 16); }
__device__ __forceinline__ float bfhi(unsigned int q) { return __uint_as_float(q & 0xFFFF0000u); }

// ---------------------------------------------------------------------------
// Kernel B: x_proj = x @ W_ih^T (scaled, bias-folded), bf16, operand-swapped:
// A = W_ih (gate rows), B = x^T (batch cols) -> C[gate j][batch].
// Stores into the 8-consumer-block layout. grid (SEQ/32, 2), block 512.
// ---------------------------------------------------------------------------
__global__ __launch_bounds__(512, 2) void gru_xproj(
    const float* __restrict__ x, const float* __restrict__ w_ih,
    const float* __restrict__ b_ih, const float* __restrict__ b_hh,
    char* __restrict__ xg)
{
    __shared__ __align__(16) char xlds[2][16384];
    const int tid = threadIdx.x;
    const int lane = tid & 63, wave = tid >> 6;
    const int l15 = lane & 15, l4 = lane >> 4;
    const int t0 = blockIdx.x * 32;
    const int gw0 = blockIdx.y * 384 + wave * 48;

    bf16x8 wa[3][8];
    float bias[3][4];
    int coffA[3];
    #pragma unroll
    for (int gt = 0; gt < 3; ++gt) {
        const int T = gw0 + gt * 16;
        const float s = (T < 256) ? -1.442695041f : ((T < 512) ? 1.442695041f : 2.885390082f);
        const int row = T + l15;
        #pragma unroll
        for (int kk = 0; kk < 8; ++kk) {
            const float* p = w_ih + row * 256 + kk * 32 + l4 * 8;
            float4 aa = *(const float4*)p;
            float4 bb = *(const float4*)(p + 4);
            union { bf16x8 v; unsigned int u[4]; } f;
            f.u[0] = pkbf(s * aa.x, s * aa.y); f.u[1] = pkbf(s * aa.z, s * aa.w);
            f.u[2] = pkbf(s * bb.x, s * bb.y); f.u[3] = pkbf(s * bb.z, s * bb.w);
            wa[gt][kk] = f.v;
        }
        #pragma unroll
        for (int q = 0; q < 4; ++q) {
            const int g = T + 4 * l4 + q;
            bias[gt][q] = (g < 512) ? s * (b_ih[g] + b_hh[g]) : s * b_ih[g];
        }
        const int gi  = T >> 8;                 // gate index r/z/n
        const int jg  = (T & 255) + 4 * l4;     // j within gate (mult of 4)
        const int wc  = jg >> 5;                // consumer wave
        const int jt  = (jg >> 4) & 1;
        const int l4c = (jg >> 2) & 3;
        coffA[gt] = (wc * 16 + l4c * 4 + (l15 & 3)) * 48 + gi * 16 + jt * 8;
    }
    const int blkpart0 = (0 * 4 + (l15 >> 2)) * 6144;   // bt = 0
    const int blkpart1 = (1 * 4 + (l15 >> 2)) * 6144;   // bt = 1

    for (int tt = 0; tt < 32; ++tt) {
        const int t = t0 + tt;
        const int buf = tt & 1;
        {
            const int b  = tid >> 4;
            const int k0 = (tid & 15) * 16;
            const float* xp = x + ((size_t)b * SEQ + t) * 256 + k0;
            float4 u0 = *(const float4*)(xp + 0);
            float4 u1 = *(const float4*)(xp + 4);
            float4 u2 = *(const float4*)(xp + 8);
            float4 u3 = *(const float4*)(xp + 12);
            union { bf16x8 v; unsigned int u[4]; } w0, w1;
            w0.u[0] = pkbf(u0.x,u0.y); w0.u[1] = pkbf(u0.z,u0.w);
            w0.u[2] = pkbf(u1.x,u1.y); w0.u[3] = pkbf(u1.z,u1.w);
            w1.u[0] = pkbf(u2.x,u2.y); w1.u[1] = pkbf(u2.z,u2.w);
            w1.u[2] = pkbf(u3.x,u3.y); w1.u[3] = pkbf(u3.z,u3.w);
            const int a0 = (b >> 4) * 8192 + (k0 >> 5) * 1024 + ((k0 >> 3) & 3) * 256 + (b & 15) * 16;
            *(bf16x8*)(xlds[buf] + a0      ) = w0.v;
            *(bf16x8*)(xlds[buf] + a0 + 256) = w1.v;
        }
        __syncthreads();

        f32x4 acc[3][2];
        #pragma unroll
        for (int gt = 0; gt < 3; ++gt)
            #pragma unroll
            for (int bt = 0; bt < 2; ++bt)
                acc[gt][bt] = (f32x4){bias[gt][0], bias[gt][1], bias[gt][2], bias[gt][3]};

        #pragma unroll
        for (int kk = 0; kk < 8; ++kk) {
            bf16x8 b0 = *(const bf16x8*)(xlds[buf] + (       kk * 1024 + l4 * 256 + l15 * 16));
            bf16x8 b1 = *(const bf16x8*)(xlds[buf] + (8192 + kk * 1024 + l4 * 256 + l15 * 16));
            #pragma unroll
            for (int gt = 0; gt < 3; ++gt) {
                acc[gt][0] = __builtin_amdgcn_mfma_f32_16x16x32_bf16(wa[gt][kk], b0, acc[gt][0], 0, 0, 0);
                acc[gt][1] = __builtin_amdgcn_mfma_f32_16x16x32_bf16(wa[gt][kk], b1, acc[gt][1], 0, 0, 0);
            }
        }
        #pragma unroll
        for (int bt = 0; bt < 2; ++bt)
            #pragma unroll
            for (int gt = 0; gt < 3; ++gt) {
                uint2 q;
                q.x = pkbf(acc[gt][bt][0], acc[gt][bt][1]);
                q.y = pkbf(acc[gt][bt][2], acc[gt][bt][3]);
                *(uint2*)(xg + (size_t)t * SLAB + (bt ? blkpart1 : blkpart0) + coffA[gt]) = q;
            }
    }
}

// ---------------------------------------------------------------------------
// Kernel C: persistent GRU scan, operand-swapped, batch-split x8, 4-way-split
// GATES. grid(8): block b owns batches [4b, 4b+4). 8 waves; wave w: hidden
// cols [32w,32w+32) x 3 gates. 5 weight tiles in regs; n-gate jt1 tile in LDS.
// h double-buffered bf16 in LDS (2KB tile, 4-lane broadcast reads).
// Dup group g = l15>>2 selects (jt = l15 bit3, ih = l15 bit2): each lane runs
// GATES for 2 h-values (6 trans). All lanes do distinct work; no predication.
// LDS: hb 4KB + wn 64KB = 68KB dynamic. Raw s_barrier + lgkmcnt(0) only.
// ---------------------------------------------------------------------------
__global__ __launch_bounds__(512, 2) void gru_rec(
    const float* __restrict__ w_hh, const float* __restrict__ b_hh,
    const float* __restrict__ h0, const char* __restrict__ xg,
    float* __restrict__ out)
{
    extern __shared__ __align__(16) char smem[];
    char* hb = smem;           // [2][2048]: [buf][kk(8)][slot(4)][b(4)][16B]
    char* wn = smem + 4096;    // [wave(8)][kk(8)][1KB] = 64KB
    const int tid = threadIdx.x, lane = tid & 63, wave = tid >> 6;
    const int l15 = lane & 15, l4 = lane >> 4;
    const int bl  = l15 & 3;             // batch lane
    const int jtl = (l15 >> 3) & 1;      // this lane's jt assignment
    const int ihl = (l15 >> 2) & 1;      // this lane's i-pair assignment
    const int blk = blockIdx.x;
    const int j0 = wave * 32;

    // tiles g6=0..4 in regs (160); g6=5 (n-gate jt1) -> LDS
    bf16x8 wf[5][8];
    #pragma unroll
    for (int g6 = 0; g6 < 6; ++g6) {
        const int gate = g6 >> 1, jt = g6 & 1;
        const int row = gate * 256 + j0 + jt * 16 + l15;
        const float s = (gate == 0) ? -1.442695041f : ((gate == 1) ? 1.442695041f : 2.885390082f);
        #pragma unroll
        for (int kk = 0; kk < 8; ++kk) {
            const float* p = w_hh + row * 256 + kk * 32 + l4 * 8;
            float4 aa = *(const float4*)p;
            float4 bb = *(const float4*)(p + 4);
            union { bf16x8 v; unsigned int u[4]; } f;
            f.u[0] = pkbf(s * aa.x, s * aa.y); f.u[1] = pkbf(s * aa.z, s * aa.w);
            f.u[2] = pkbf(s * bb.x, s * bb.y); f.u[3] = pkbf(s * bb.z, s * bb.w);
            if (g6 < 5) wf[g6][kk] = f.v;
            else *(bf16x8*)(wn + ((wave * 8 + kk) * 1024 + lane * 16)) = f.v;
        }
    }
    // n-gate b_hh, scaled, packed bf16 (both jt halves needed for acc-init)
    uint2 bHnP[2];
    #pragma unroll
    for (int jt = 0; jt < 2; ++jt) {
        const int j = j0 + jt * 16 + 4 * l4;
        bHnP[jt].x = pkbf(2.885390082f * b_hh[512 + j + 0], 2.885390082f * b_hh[512 + j + 1]);
        bHnP[jt].y = pkbf(2.885390082f * b_hh[512 + j + 2], 2.885390082f * b_hh[512 + j + 3]);
    }

    // LDS bases (per-step offsets are compile-time immediates)
    // write: this lane's 2 bf16 at j = j0 + jtl*16 + 4*l4 + 2*ihl (+0,+1)
    char* hwp = hb + (wave * 256 + (2 * jtl + (l4 >> 1)) * 64 + bl * 16
                      + ((l4 & 1) * 4 + 2 * ihl) * 2);
    const char* hrp = hb + (l4 * 64 + bl * 16);
    const char* wnp = wn + (wave * 8192 + lane * 16);

    // initial h: lane owns (batch=bl, j = j0 + jtl*16 + 4*l4 + 2*ihl + {0,1})
    float hprev[2];
    {
        const float* hp0 = h0 + (blk * 4 + bl) * 256 + j0 + jtl * 16 + 4 * l4 + 2 * ihl;
        hprev[0] = hp0[0]; hprev[1] = hp0[1];
        *(unsigned int*)hwp = pkbf(hprev[0], hprev[1]);
    }

    const char* xqb = xg + blk * 6144 + wave * 768 + l4 * 192 + bl * 48;
    char* op = (char*)out + ((size_t)(blk * 4 + bl) * SEQ * 256
                             + j0 + jtl * 16 + 4 * l4 + 2 * ihl) * 4;

    // distance-1 prefetch: single slot (12 regs)
    uint4 xq0 = *(const uint4*)(xqb + 0);
    uint4 xq1 = *(const uint4*)(xqb + 16);
    uint4 xq2 = *(const uint4*)(xqb + 32);
    const char* xqn = xqb + SLAB;

    asm volatile("s_waitcnt lgkmcnt(0)" ::: "memory");
    __builtin_amdgcn_s_barrier();
    __builtin_amdgcn_sched_barrier(0);

#define BODY(T_, P_) do { \
    f32x4 acc0 = { bflo(xq0.x), bfhi(xq0.x), bflo(xq0.y), bfhi(xq0.y) }; \
    f32x4 acc1 = { bflo(xq0.z), bfhi(xq0.z), bflo(xq0.w), bfhi(xq0.w) }; \
    f32x4 acc2 = { bflo(xq1.x), bfhi(xq1.x), bflo(xq1.y), bfhi(xq1.y) }; \
    f32x4 acc3 = { bflo(xq1.z), bfhi(xq1.z), bflo(xq1.w), bfhi(xq1.w) }; \
    f32x4 acc4 = { bflo(bHnP[0].x), bfhi(bHnP[0].x), bflo(bHnP[0].y), bfhi(bHnP[0].y) }; \
    f32x4 acc5 = { bflo(bHnP[1].x), bfhi(bHnP[1].x), bflo(bHnP[1].y), bfhi(bHnP[1].y) }; \
    xq0 = *(const uint4*)(xqn + 0); \
    xq1 = *(const uint4*)(xqn + 16); \
    _Pragma("unroll") for (int kk = 0; kk < 8; ++kk) { \
        bf16x8 h_ = *(const bf16x8*)(hrp + (kk * 256 + (P_) * 2048)); \
        bf16x8 w5 = *(const bf16x8*)(wnp + (kk * 1024)); \
        acc0 = __builtin_amdgcn_mfma_f32_16x16x32_bf16(wf[0][kk], h_, acc0, 0, 0, 0); \
        acc1 = __builtin_amdgcn_mfma_f32_16x16x32_bf16(wf[1][kk], h_, acc1, 0, 0, 0); \
        acc2 = __builtin_amdgcn_mfma_f32_16x16x32_bf16(wf[2][kk], h_, acc2, 0, 0, 0); \
        acc3 = __builtin_amdgcn_mfma_f32_16x16x32_bf16(wf[3][kk], h_, acc3, 0, 0, 0); \
        acc4 = __builtin_amdgcn_mfma_f32_16x16x32_bf16(wf[4][kk], h_, acc4, 0, 0, 0); \
        acc5 = __builtin_amdgcn_mfma_f32_16x16x32_bf16(w5, h_, acc5, 0, 0, 0); \
    } \
    /* 4-way-split GATES: lane handles values v=0,1 at i = 2*ihl+v, jt = jtl */ \
    const unsigned qn0 = jtl ? xq2.z : xq2.x; \
    const unsigned qn1 = jtl ? xq2.w : xq2.y; \
    const unsigned qn  = ihl ? qn1 : qn0; \
    float xn[2] = { bflo(qn), bfhi(qn) }; \
    _Pragma("unroll") for (int v = 0; v < 2; ++v) { \
        float r0 = ihl ? acc0[2 + v] : acc0[v]; \
        float r1 = ihl ? acc1[2 + v] : acc1[v]; \
        float ar = jtl ? r1 : r0; \
        float z0 = ihl ? acc2[2 + v] : acc2[v]; \
        float z1 = ihl ? acc3[2 + v] : acc3[v]; \
        float az = jtl ? z1 : z0; \
        float n0 = ihl ? acc4[2 + v] : acc4[v]; \
        float n1 = ihl ? acc5[2 + v] : acc5[v]; \
        float an = jtl ? n1 : n0; \
        float r   = __builtin_amdgcn_rcpf(1.0f + __builtin_amdgcn_exp2f(ar)); \
        float uu  = __builtin_amdgcn_rcpf(1.0f + __builtin_amdgcn_exp2f(az)); \
        float pre = fmaf(r, an, xn[v]); \
        float nn  = fmaf(-2.0f, __builtin_amdgcn_rcpf(1.0f + __builtin_amdgcn_exp2f(pre)), 1.0f); \
        float hp  = hprev[v]; \
        hprev[v] = fmaf(uu, nn - hp, hp); \
    } \
    *(unsigned int*)(hwp + (1 - (P_)) * 2048) = pkbf(hprev[0], hprev[1]); \
    { float2 st = { hprev[0], hprev[1] }; *(float2*)op = st; } \
    xq2 = *(const uint4*)(xqn + 32); \
    if ((T_) + 2 < SEQ) xqn += SLAB; \
    op += 1024; \
    __builtin_amdgcn_sched_barrier(0); \
    asm volatile("s_waitcnt lgkmcnt(0)" ::: "memory"); \
    __builtin_amdgcn_s_barrier(); \
    __builtin_amdgcn_sched_barrier(0); \
} while (0)

    for (int tt = 0; tt < SEQ; tt += 2) {
        BODY(tt + 0, 0);
        BODY(tt + 1, 1);
    }
#undef BODY
}

extern "C" void kernel_launch(void* const* d_in, const int* in_sizes, int n_in,
                              void* d_out, int out_size, void* d_ws, size_t ws_size,
                              hipStream_t stream) {
    const float* x    = (const float*)d_in[0];
    const float* h0   = (const float*)d_in[1];
    const float* w_ih = (const float*)d_in[2];
    const float* w_hh = (const float*)d_in[3];
    const float* b_ih = (const float*)d_in[4];
    const float* b_hh = (const float*)d_in[5];
    float* out = (float*)d_out;
    char* xg = (char*)d_ws;   // needs SEQ*49152 = 192 MB

    (void)in_sizes; (void)n_in; (void)out_size; (void)ws_size;

    hipFuncSetAttribute((const void*)gru_rec,
                        hipFuncAttributeMaxDynamicSharedMemorySize, 69632);

    gru_xproj<<<dim3(SEQ / 32, 2), dim3(512), 0, stream>>>(x, w_ih, b_ih, b_hh, xg);
    gru_rec<<<dim3(8), dim3(512), 69632, stream>>>(w_hh, b_hh, h0, xg, out);
}